// Round 8
// baseline (2184.740 us; speedup 1.0000x reference)
//
#include <hip/hip_runtime.h>

#define T 4096

// tanh(x) = 1 - 2/(exp(2x)+1). v_exp_f32 + v_rcp_f32, branch-free, ~30 cyc.
// Exonerated by R2 vs R3: identical absmax with/without -> error below bf16
// rounding even through 4096 recurrent steps. Saturates correctly at +/-1.
__device__ __forceinline__ float fast_tanh(float x) {
    float e = __expf(2.0f * x);
    float r = __builtin_amdgcn_rcpf(e + 1.0f);
    return fmaf(-2.0f, r, 1.0f);
}

// broadcast lane j's value of v to all lanes via v_readlane (SGPR result,
// usable directly as the scalar operand of v_fma_f32 — no LDS round-trip).
__device__ __forceinline__ float lane_bcast(float v, int j) {
    return __uint_as_float(__builtin_amdgcn_readlane(__float_as_uint(v), j));
}

// ---------------------------------------------------------------------------
// prep: pre[s][t][i] = b_ih0[i] + b_hh0[i] + sum_d W_ih0[i][d] * in[0,t,d]
// Only batch element 0 of x / y matters (reference uses e[0], o[0] only).
// ---------------------------------------------------------------------------
__global__ void prep_kernel(const float* __restrict__ x, const float* __restrict__ y,
                            const float* __restrict__ eW, const float* __restrict__ ebi,
                            const float* __restrict__ ebh,
                            const float* __restrict__ oW, const float* __restrict__ obi,
                            const float* __restrict__ obh,
                            float* __restrict__ pre)
{
    int idx = blockIdx.x * blockDim.x + threadIdx.x;   // 2*T*64 threads
    int i = idx & 63;
    int t = (idx >> 6) & (T - 1);
    int s = idx >> 18;
    const float* in = s ? y : x;          // batch 0 = first T*3 floats
    const float* W  = s ? oW : eW;        // [64][3]
    const float* bi = s ? obi : ebi;
    const float* bh = s ? obh : ebh;
    float v = bi[i] + bh[i]
            + W[i*3+0]*in[t*3+0] + W[i*3+1]*in[t*3+1] + W[i*3+2]*in[t*3+2];
    pre[idx] = v;
}

// ---------------------------------------------------------------------------
// seq: 2 waves per RNN, TWO timesteps per barrier slot (halves the per-slot
// fixed cost: rendezvous, pre-barrier waitcnt, loop/guard machinery).
// Own-wave recurrences stay in registers (readlane broadcast, R7); LDS ring
// buffers (8-deep) carry only cross-wave flows, always >= 1 slot old:
//   wave0 @ slot k: for t in {2k, 2k+1}:  qp0[t-1] = b1 + Wih1[:,0:32]@h0[t-1][0:32]
//                                         h0[t] = tanh(p[t] + Whh0@h0[t-1]); publish
//                  (at t==T: qp0[T-1] only — R4 bugfix)
//   wave1 @ slot k: for s in {2k-3, 2k-2}: h1[s] = tanh(Whh1@h1[s-1] + qp0[s]
//                                         + Wih1[:,32:]@h0[s][32:])
// Index safety (mod 8): writer {2k-1,2k} / reader {2k+5,2k+6} for qbuf,
// writer {2k,2k+1} / reader {2k+5,2k+6} for h0lds — disjoint residues.
// ---------------------------------------------------------------------------
__global__ __launch_bounds__(128, 1) void seq_kernel(
    const float* __restrict__ pre,            // [2][T][64]
    const float* __restrict__ eWhh0, const float* __restrict__ eWih1,
    const float* __restrict__ eWhh1, const float* __restrict__ ebih1,
    const float* __restrict__ ebhh1,
    const float* __restrict__ oWhh0, const float* __restrict__ oWih1,
    const float* __restrict__ oWhh1, const float* __restrict__ obih1,
    const float* __restrict__ obhh1,
    float* __restrict__ hlast)                // [2][64]
{
    const int s    = blockIdx.x;
    const int wv   = threadIdx.x >> 6;
    const int lane = threadIdx.x & 63;

    __shared__ __align__(16) float h0lds[8][64];   // h0[t] ring
    __shared__ __align__(16) float qbuf[8][64];    // qp0[t] ring

    const float* Whh0 = s ? oWhh0 : eWhh0;
    const float* Wih1 = s ? oWih1 : eWih1;
    const float* Whh1 = s ? oWhh1 : eWhh1;
    const float  b1   = s ? (obih1[lane] + obhh1[lane])
                          : (ebih1[lane] + ebhh1[lane]);
    const float* p    = pre + s * T * 64;

    const int KMAX = T / 2 + 1;               // k = 0..2049

    if (wv == 0) {
        // -------- layer-0 wave: 96 weight floats (stays in VGPRs) --------
        float w0[64], wlo[32];
#pragma unroll
        for (int j = 0; j < 64; ++j) w0[j]  = Whh0[lane * 64 + j];
#pragma unroll
        for (int j = 0; j < 32; ++j) wlo[j] = Wih1[lane * 64 + j];

        float hp  = 0.f;                       // h0[t-1]
        float pc0 = p[lane];                   // p[0]
        float pc1 = p[64 + lane];              // p[1]
        for (int k = 0; k <= KMAX; ++k) {
            const int t0 = 2 * k, t1 = 2 * k + 1;
            // prefetch next slot's p (off critical path)
            float pn0 = (t0 + 2 < T) ? p[(t0 + 2) * 64 + lane] : 0.f;
            float pn1 = (t1 + 2 < T) ? p[(t1 + 2) * 64 + lane] : 0.f;

            if (t0 <= T) {                     // substep A (t0 even; t0==T -> q only)
                float aa[4] = {0.f, 0.f, 0.f, 0.f};
                float qq[4] = {0.f, 0.f, 0.f, 0.f};
#pragma unroll
                for (int j = 0; j < 64; ++j) {
                    float hj = lane_bcast(hp, j);            // h0[t0-1][j]
                    aa[j & 3] = fmaf(w0[j], hj, aa[j & 3]);
                    if (j < 32) qq[j & 3] = fmaf(wlo[j], hj, qq[j & 3]);
                }
                qbuf[(t0 + 7) & 7][lane] = b1 + ((qq[0] + qq[1]) + (qq[2] + qq[3]));
                if (t0 < T) {
                    hp = fast_tanh(pc0 + ((aa[0] + aa[1]) + (aa[2] + aa[3])));
                    h0lds[t0 & 7][lane] = hp;
                }
            }
            if (t1 < T) {                      // substep B (t1 odd, never == T)
                float aa[4] = {0.f, 0.f, 0.f, 0.f};
                float qq[4] = {0.f, 0.f, 0.f, 0.f};
#pragma unroll
                for (int j = 0; j < 64; ++j) {
                    float hj = lane_bcast(hp, j);            // h0[t0][j]
                    aa[j & 3] = fmaf(w0[j], hj, aa[j & 3]);
                    if (j < 32) qq[j & 3] = fmaf(wlo[j], hj, qq[j & 3]);
                }
                qbuf[(t1 + 7) & 7][lane] = b1 + ((qq[0] + qq[1]) + (qq[2] + qq[3]));
                hp = fast_tanh(pc1 + ((aa[0] + aa[1]) + (aa[2] + aa[3])));
                h0lds[t1 & 7][lane] = hp;
            }
            pc0 = pn0; pc1 = pn1;
            __syncthreads();
        }
    } else {
        // -------- layer-1 wave: 96 weight floats --------
        float whi[32], w1[64];
#pragma unroll
        for (int j = 0; j < 32; ++j) whi[j] = Wih1[lane * 64 + 32 + j];
#pragma unroll
        for (int j = 0; j < 64; ++j) w1[j]  = Whh1[lane * 64 + j];

        float hp = 0.f;                        // h1[s-1]
        for (int k = 0; k <= KMAX; ++k) {
            const int s0 = 2 * k - 3, s1 = 2 * k - 2;
#pragma unroll
            for (int sub = 0; sub < 2; ++sub) {
                const int ss = sub ? s1 : s0;
                if (ss >= 0 && ss < T) {
                    // LDS loads issued first; results consumed at chain END.
                    float qb = qbuf[ss & 7][lane];           // qp0[ss]
                    const float4* hv = ((const float4*)h0lds[ss & 7]) + 8;
                    float q[4] = {0.f, 0.f, 0.f, 0.f};
#pragma unroll
                    for (int j4 = 0; j4 < 8; ++j4) {
                        float4 u = hv[j4];
                        q[0] = fmaf(whi[4*j4+0], u.x, q[0]);
                        q[1] = fmaf(whi[4*j4+1], u.y, q[1]);
                        q[2] = fmaf(whi[4*j4+2], u.z, q[2]);
                        q[3] = fmaf(whi[4*j4+3], u.w, q[3]);
                    }
                    float cc[4] = {0.f, 0.f, 0.f, 0.f};
#pragma unroll
                    for (int j = 0; j < 64; ++j) {
                        float hj = lane_bcast(hp, j);        // h1[ss-1][j]
                        cc[j & 3] = fmaf(w1[j], hj, cc[j & 3]);
                    }
                    hp = fast_tanh(((cc[0] + cc[1]) + (cc[2] + cc[3]))
                                   + (qb + ((q[0] + q[1]) + (q[2] + q[3]))));
                }
            }
            __syncthreads();
        }
        hlast[s * 64 + lane] = hp;             // h1[T-1]
    }
}

// ---------------------------------------------------------------------------
// head: e0 = fce_w@hx + fce_b ; o0 = fco_w@hy + fco_b ; zz=[e0,o0,z];
//       h = relu(fc1_w@zz + fc1_b) ; out = fc2_w@h + fc2_b
// ---------------------------------------------------------------------------
__global__ void head_kernel(const float* __restrict__ hlast,   // [2][64]
                            const float* __restrict__ z,
                            const float* __restrict__ fce_w, const float* __restrict__ fce_b,
                            const float* __restrict__ fco_w, const float* __restrict__ fco_b,
                            const float* __restrict__ fc1_w, const float* __restrict__ fc1_b,
                            const float* __restrict__ fc2_w, const float* __restrict__ fc2_b,
                            float* __restrict__ out)            // [5]
{
    const int lane = threadIdx.x;   // 64 threads
    __shared__ float zz[9];
    __shared__ float hh[64];

    if (lane < 2) {
        float sacc = fce_b[lane];
        for (int j = 0; j < 64; ++j) sacc += fce_w[lane * 64 + j] * hlast[j];
        zz[lane] = sacc;
    } else if (lane < 4) {
        int r = lane - 2;
        float sacc = fco_b[r];
        for (int j = 0; j < 64; ++j) sacc += fco_w[r * 64 + j] * hlast[64 + j];
        zz[lane] = sacc;
    } else if (lane < 9) {
        zz[lane] = z[lane - 4];
    }
    __syncthreads();

    float sacc = fc1_b[lane];
#pragma unroll
    for (int j = 0; j < 9; ++j) sacc += fc1_w[lane * 9 + j] * zz[j];
    hh[lane] = fmaxf(sacc, 0.f);
    __syncthreads();

    if (lane < 5) {
        float o = fc2_b[lane];
        for (int i = 0; i < 64; ++i) o += fc2_w[lane * 64 + i] * hh[i];
        out[lane] = o;
    }
}

// ---------------------------------------------------------------------------
extern "C" void kernel_launch(void* const* d_in, const int* in_sizes, int n_in,
                              void* d_out, int out_size, void* d_ws, size_t ws_size,
                              hipStream_t stream)
{
    const float* x      = (const float*)d_in[0];
    const float* y      = (const float*)d_in[1];
    const float* z      = (const float*)d_in[2];
    const float* e_Wih0 = (const float*)d_in[3];
    const float* e_Whh0 = (const float*)d_in[4];
    const float* e_bih0 = (const float*)d_in[5];
    const float* e_bhh0 = (const float*)d_in[6];
    const float* e_Wih1 = (const float*)d_in[7];
    const float* e_Whh1 = (const float*)d_in[8];
    const float* e_bih1 = (const float*)d_in[9];
    const float* e_bhh1 = (const float*)d_in[10];
    const float* o_Wih0 = (const float*)d_in[11];
    const float* o_Whh0 = (const float*)d_in[12];
    const float* o_bih0 = (const float*)d_in[13];
    const float* o_bhh0 = (const float*)d_in[14];
    const float* o_Wih1 = (const float*)d_in[15];
    const float* o_Whh1 = (const float*)d_in[16];
    const float* o_bih1 = (const float*)d_in[17];
    const float* o_bhh1 = (const float*)d_in[18];
    const float* fce_w  = (const float*)d_in[19];
    const float* fce_b  = (const float*)d_in[20];
    const float* fco_w  = (const float*)d_in[21];
    const float* fco_b  = (const float*)d_in[22];
    const float* fc1_w  = (const float*)d_in[23];
    const float* fc1_b  = (const float*)d_in[24];
    const float* fc2_w  = (const float*)d_in[25];
    const float* fc2_b  = (const float*)d_in[26];

    float* pre   = (float*)d_ws;            // 2*T*64 floats = 2 MB
    float* hlast = pre + 2 * T * 64;        // 128 floats
    float* out   = (float*)d_out;

    prep_kernel<<<(2 * T * 64) / 256, 256, 0, stream>>>(
        x, y, e_Wih0, e_bih0, e_bhh0, o_Wih0, o_bih0, o_bhh0, pre);

    seq_kernel<<<2, 128, 0, stream>>>(
        pre,
        e_Whh0, e_Wih1, e_Whh1, e_bih1, e_bhh1,
        o_Whh0, o_Wih1, o_Whh1, o_bih1, o_bhh1,
        hlast);

    head_kernel<<<1, 64, 0, stream>>>(
        hlast, z, fce_w, fce_b, fco_w, fco_b, fc1_w, fc1_b, fc2_w, fc2_b, out);
}

// Round 9
// 1195.523 us; speedup vs baseline: 1.8274x; 1.8274x over previous
//
#include <hip/hip_runtime.h>

#define T 4096
#define EP 8                      // steps per barrier epoch
#define RING 32                   // LDS ring depth (disjoint writer/reader mod 32)
#define NEP (T / EP + 2)          // 514 epochs: wave1 lags wave0 by 2 epochs

// tanh(x) = 1 - 2/(exp(2x)+1). Branch-free, ~1e-6 err; exonerated R2 vs R3
// (identical absmax with/without over 4096 recurrent steps).
__device__ __forceinline__ float fast_tanh(float x) {
    float e = __expf(2.0f * x);
    float r = __builtin_amdgcn_rcpf(e + 1.0f);
    return fmaf(-2.0f, r, 1.0f);
}

// v_readlane broadcast (SGPR result usable as the scalar FMA operand).
__device__ __forceinline__ float lane_bcast(float v, int j) {
    return __uint_as_float(__builtin_amdgcn_readlane(__float_as_uint(v), j));
}

// ---------------------------------------------------------------------------
// prep: pre[s][t][i] = b_ih0[i] + b_hh0[i] + sum_d W_ih0[i][d] * in[0,t,d]
// Only batch element 0 of x / y matters (reference uses e[0], o[0] only).
// ---------------------------------------------------------------------------
__global__ void prep_kernel(const float* __restrict__ x, const float* __restrict__ y,
                            const float* __restrict__ eW, const float* __restrict__ ebi,
                            const float* __restrict__ ebh,
                            const float* __restrict__ oW, const float* __restrict__ obi,
                            const float* __restrict__ obh,
                            float* __restrict__ pre)
{
    int idx = blockIdx.x * blockDim.x + threadIdx.x;   // 2*T*64 threads
    int i = idx & 63;
    int t = (idx >> 6) & (T - 1);
    int s = idx >> 18;
    const float* in = s ? y : x;          // batch 0 = first T*3 floats
    const float* W  = s ? oW : eW;        // [64][3]
    const float* bi = s ? obi : ebi;
    const float* bh = s ? obh : ebh;
    float v = bi[i] + bh[i]
            + W[i*3+0]*in[t*3+0] + W[i*3+1]*in[t*3+1] + W[i*3+2]*in[t*3+2];
    pre[idx] = v;
}

// ---------------------------------------------------------------------------
// seq: 3 specialized waves per RNN, barrier once per EP(=8)-step epoch.
//   wave0 @ epoch k: h0[t] = tanh(p[t] + Whh0@h0[t-1]), t in [8k, 8k+8)
//                    (pure register recurrence via readlane; publish to ring)
//   wave1 (helper) @ epoch k: qfull[t] = b1 + Wih1@h0[t], t in [8k-8, 8k)
//                    (LDS b128 broadcast reads; a full epoch of slack)
//   wave2 @ epoch k: h1[t] = tanh(qfull[t] + Whh1@h1[t-1]), t in [8k-16, 8k-8)
// Ring safety (mod 32): within one epoch writers/readers touch disjoint sets
// {8k..8k+7} vs {8k-8..8k-1} (h0ring) and {8k-8..8k-1} vs {8k-16..8k-9}
// (qring); readers always see entries published before >=1 barrier.
// Readlanes batched in 8s (live SGPR batch) to break write->read adjacency.
// ---------------------------------------------------------------------------
__global__ __launch_bounds__(192, 1) void seq_kernel(
    const float* __restrict__ pre,            // [2][T][64]
    const float* __restrict__ eWhh0, const float* __restrict__ eWih1,
    const float* __restrict__ eWhh1, const float* __restrict__ ebih1,
    const float* __restrict__ ebhh1,
    const float* __restrict__ oWhh0, const float* __restrict__ oWih1,
    const float* __restrict__ oWhh1, const float* __restrict__ obih1,
    const float* __restrict__ obhh1,
    float* __restrict__ hlast)                // [2][64]
{
    const int s    = blockIdx.x;
    const int wv   = threadIdx.x >> 6;
    const int lane = threadIdx.x & 63;

    __shared__ __align__(16) float h0ring[RING][64];
    __shared__ __align__(16) float qring[RING][64];

    const float* p = pre + s * T * 64;

    if (wv == 0) {
        // ---------- layer-0 recurrence wave ----------
        const float* Whh0 = s ? oWhh0 : eWhh0;
        float w0[64];
#pragma unroll
        for (int j = 0; j < 64; ++j) w0[j] = Whh0[lane * 64 + j];

        float hp = 0.f;                        // h0[t-1]
        float pc[EP], pn[EP];
#pragma unroll
        for (int i = 0; i < EP; ++i) pc[i] = p[i * 64 + lane];

        for (int k = 0; k < NEP; ++k) {
            const int base = k * EP;
            // prefetch next epoch's p (consumed next epoch -> latency hidden)
#pragma unroll
            for (int i = 0; i < EP; ++i) {
                int t = base + EP + i;
                pn[i] = (t < T) ? p[t * 64 + lane] : 0.f;
            }
            if (base < T) {                    // wave-uniform scalar branch
#pragma unroll
                for (int i = 0; i < EP; ++i) {
                    float aa[4] = { pc[i], 0.f, 0.f, 0.f };
#pragma unroll
                    for (int jb = 0; jb < 64; jb += 8) {
                        float hj[8];
#pragma unroll
                        for (int u = 0; u < 8; ++u) hj[u] = lane_bcast(hp, jb + u);
#pragma unroll
                        for (int u = 0; u < 8; ++u)
                            aa[u & 3] = fmaf(w0[jb + u], hj[u], aa[u & 3]);
                    }
                    hp = fast_tanh((aa[0] + aa[1]) + (aa[2] + aa[3]));
                    h0ring[(base + i) & (RING - 1)][lane] = hp;   // publish
                }
            }
#pragma unroll
            for (int i = 0; i < EP; ++i) pc[i] = pn[i];
            __syncthreads();
        }
    } else if (wv == 1) {
        // ---------- helper wave: full input projection for layer 1 ----------
        const float* Wih1 = s ? oWih1 : eWih1;
        const float  b1   = s ? (obih1[lane] + obhh1[lane])
                              : (ebih1[lane] + ebhh1[lane]);
        float wi[64];
#pragma unroll
        for (int j = 0; j < 64; ++j) wi[j] = Wih1[lane * 64 + j];

        for (int k = 0; k < NEP; ++k) {
            const int base = k * EP - EP;
            if (base >= 0 && base < T) {
#pragma unroll
                for (int i = 0; i < EP; ++i) {
                    const int t = base + i;
                    const float4* hv = (const float4*)h0ring[t & (RING - 1)];
                    float q[4] = { b1, 0.f, 0.f, 0.f };
#pragma unroll
                    for (int j4 = 0; j4 < 16; ++j4) {
                        float4 u = hv[j4];
                        q[0] = fmaf(wi[4*j4+0], u.x, q[0]);
                        q[1] = fmaf(wi[4*j4+1], u.y, q[1]);
                        q[2] = fmaf(wi[4*j4+2], u.z, q[2]);
                        q[3] = fmaf(wi[4*j4+3], u.w, q[3]);
                    }
                    qring[t & (RING - 1)][lane] = (q[0] + q[1]) + (q[2] + q[3]);
                }
            }
            __syncthreads();
        }
    } else {
        // ---------- layer-1 recurrence wave ----------
        const float* Whh1 = s ? oWhh1 : eWhh1;
        float w1[64];
#pragma unroll
        for (int j = 0; j < 64; ++j) w1[j] = Whh1[lane * 64 + j];

        float hp = 0.f;                        // h1[t-1]
        for (int k = 0; k < NEP; ++k) {
            const int base = k * EP - 2 * EP;
            if (base >= 0) {                   // base+EP-1 <= T-1 by construction
                float qb[EP];
#pragma unroll
                for (int i = 0; i < EP; ++i)   // all written >=1 epoch ago
                    qb[i] = qring[(base + i) & (RING - 1)][lane];
#pragma unroll
                for (int i = 0; i < EP; ++i) {
                    float cc[4] = { qb[i], 0.f, 0.f, 0.f };
#pragma unroll
                    for (int jb = 0; jb < 64; jb += 8) {
                        float hj[8];
#pragma unroll
                        for (int u = 0; u < 8; ++u) hj[u] = lane_bcast(hp, jb + u);
#pragma unroll
                        for (int u = 0; u < 8; ++u)
                            cc[u & 3] = fmaf(w1[jb + u], hj[u], cc[u & 3]);
                    }
                    hp = fast_tanh((cc[0] + cc[1]) + (cc[2] + cc[3]));
                }
            }
            __syncthreads();
        }
        hlast[s * 64 + lane] = hp;             // h1[T-1]
    }
}

// ---------------------------------------------------------------------------
// head: e0 = fce_w@hx + fce_b ; o0 = fco_w@hy + fco_b ; zz=[e0,o0,z];
//       h = relu(fc1_w@zz + fc1_b) ; out = fc2_w@h + fc2_b
// ---------------------------------------------------------------------------
__global__ void head_kernel(const float* __restrict__ hlast,   // [2][64]
                            const float* __restrict__ z,
                            const float* __restrict__ fce_w, const float* __restrict__ fce_b,
                            const float* __restrict__ fco_w, const float* __restrict__ fco_b,
                            const float* __restrict__ fc1_w, const float* __restrict__ fc1_b,
                            const float* __restrict__ fc2_w, const float* __restrict__ fc2_b,
                            float* __restrict__ out)            // [5]
{
    const int lane = threadIdx.x;   // 64 threads
    __shared__ float zz[9];
    __shared__ float hh[64];

    if (lane < 2) {
        float sacc = fce_b[lane];
        for (int j = 0; j < 64; ++j) sacc += fce_w[lane * 64 + j] * hlast[j];
        zz[lane] = sacc;
    } else if (lane < 4) {
        int r = lane - 2;
        float sacc = fco_b[r];
        for (int j = 0; j < 64; ++j) sacc += fco_w[r * 64 + j] * hlast[64 + j];
        zz[lane] = sacc;
    } else if (lane < 9) {
        zz[lane] = z[lane - 4];
    }
    __syncthreads();

    float sacc = fc1_b[lane];
#pragma unroll
    for (int j = 0; j < 9; ++j) sacc += fc1_w[lane * 9 + j] * zz[j];
    hh[lane] = fmaxf(sacc, 0.f);
    __syncthreads();

    if (lane < 5) {
        float o = fc2_b[lane];
        for (int i = 0; i < 64; ++i) o += fc2_w[lane * 64 + i] * hh[i];
        out[lane] = o;
    }
}

// ---------------------------------------------------------------------------
extern "C" void kernel_launch(void* const* d_in, const int* in_sizes, int n_in,
                              void* d_out, int out_size, void* d_ws, size_t ws_size,
                              hipStream_t stream)
{
    const float* x      = (const float*)d_in[0];
    const float* y      = (const float*)d_in[1];
    const float* z      = (const float*)d_in[2];
    const float* e_Wih0 = (const float*)d_in[3];
    const float* e_Whh0 = (const float*)d_in[4];
    const float* e_bih0 = (const float*)d_in[5];
    const float* e_bhh0 = (const float*)d_in[6];
    const float* e_Wih1 = (const float*)d_in[7];
    const float* e_Whh1 = (const float*)d_in[8];
    const float* e_bih1 = (const float*)d_in[9];
    const float* e_bhh1 = (const float*)d_in[10];
    const float* o_Wih0 = (const float*)d_in[11];
    const float* o_Whh0 = (const float*)d_in[12];
    const float* o_bih0 = (const float*)d_in[13];
    const float* o_bhh0 = (const float*)d_in[14];
    const float* o_Wih1 = (const float*)d_in[15];
    const float* o_Whh1 = (const float*)d_in[16];
    const float* o_bih1 = (const float*)d_in[17];
    const float* o_bhh1 = (const float*)d_in[18];
    const float* fce_w  = (const float*)d_in[19];
    const float* fce_b  = (const float*)d_in[20];
    const float* fco_w  = (const float*)d_in[21];
    const float* fco_b  = (const float*)d_in[22];
    const float* fc1_w  = (const float*)d_in[23];
    const float* fc1_b  = (const float*)d_in[24];
    const float* fc2_w  = (const float*)d_in[25];
    const float* fc2_b  = (const float*)d_in[26];

    float* pre   = (float*)d_ws;            // 2*T*64 floats = 2 MB
    float* hlast = pre + 2 * T * 64;        // 128 floats
    float* out   = (float*)d_out;

    prep_kernel<<<(2 * T * 64) / 256, 256, 0, stream>>>(
        x, y, e_Wih0, e_bih0, e_bhh0, o_Wih0, o_bih0, o_bhh0, pre);

    seq_kernel<<<2, 192, 0, stream>>>(
        pre,
        e_Whh0, e_Wih1, e_Whh1, e_bih1, e_bhh1,
        o_Whh0, o_Wih1, o_Whh1, o_bih1, o_bhh1,
        hlast);

    head_kernel<<<1, 64, 0, stream>>>(
        hlast, z, fce_w, fce_b, fco_w, fco_b, fc1_w, fc1_b, fc2_w, fc2_b, out);
}